// Round 12
// baseline (1364.003 us; speedup 1.0000x reference)
//
#include <hip/hip_runtime.h>
#include <hip/hip_cooperative_groups.h>
#include <math.h>

namespace cg = cooperative_groups;

#define NN 10000
#define NE 160000
#define CAP 128     // bucket capacity; P(in-deg >= 128 | Poisson(16)) ~ 1e-60
#define NT 256
#define WC1_TOTAL (782 * 48)
#define WC5_TOTAL (128 * 60)
#define L1_SPLITS 12
#define L1_KCHUNK 66   // even (float2 path); 12*66 >= 782

struct MegaParams {
  const float* x;
  const int* src;
  const int* dst;
  const float* W1; const float* b1;
  const float* W2; const float* b2;
  const float* W3; const float* b3;
  const float* W4; const float* b4;
  const float* W5; const float* b5;
  int* deg; int* cnt; int* bsrc;
  float* dinv; float* wc1; float* wc5;
  float* ABC1; float* E1; float* B2; float* B3; float* B4;
  float* H4; float* ABC5; float* E5; float* P;
  float* out;
};

// ---- weight concat: Wc [Fin][3*Fp]: [W0-W2 | W1 | W2], pad cols zero ----
__device__ __forceinline__ void wcat_one(const float* __restrict__ W,
                                         float* __restrict__ Wc,
                                         int i, int Fin, int F, int Fp) {
  int w3 = 3 * Fp;
  int row = i / w3;
  int c = i - row * w3;
  int sec = c / Fp;
  int f = c - sec * Fp;
  float v = 0.0f;
  if (f < F) {
    if (sec == 0)      v = W[row * F + f] - W[2 * Fin * F + row * F + f];
    else if (sec == 1) v = W[Fin * F + row * F + f];
    else               v = W[2 * Fin * F + row * F + f];
  }
  Wc[i] = v;
}

// ---------------- stage bodies (shared by mega + fallback) ------------------

__device__ void stage_zero(const MegaParams& p) {
  int tid = blockIdx.x * NT + threadIdx.x;
  int TT = gridDim.x * NT;
  for (int i = tid; i < 2 * NN; i += TT) p.deg[i] = 0;   // deg+cnt contiguous
  for (int i = tid; i < WC1_TOTAL; i += TT) wcat_one(p.W1, p.wc1, i, 782, 16, 16);
  for (int i = tid; i < WC5_TOTAL; i += TT) wcat_one(p.W5, p.wc5, i, 128, 19, 20);
}

__device__ void stage_count(const MegaParams& p) {
  int tid = blockIdx.x * NT + threadIdx.x;
  int TT = gridDim.x * NT;
  for (int e = tid; e < NE; e += TT) {
    int s = p.src[e], d = p.dst[e];
    atomicAdd(&p.deg[s], 1);
    int slot = atomicAdd(&p.cnt[d], 1);
    if (slot < CAP) p.bsrc[(d << 7) + slot] = s;
  }
}

__device__ void stage_dinv_reduce(const MegaParams& p) {
  int tid = blockIdx.x * NT + threadIdx.x;
  int TT = gridDim.x * NT;
  for (int i = tid; i < NN; i += TT) {
    int d = p.deg[i];
    p.dinv[i] = d > 0 ? 1.0f / sqrtf((float)d) : 0.0f;
  }
  for (int i = tid; i < NN * 48; i += TT) {
    float s = 0.f;
#pragma unroll
    for (int z = 0; z < L1_SPLITS; z++) s += p.P[(size_t)z * (NN * 48) + i];
    p.ABC1[i] = s;
  }
}

// ---- GEMM stage (register-X prefetch, LDS-W broadcast, RT=1) ----
struct Row8 { float4 lo, hi; };

template <bool AL16>
__device__ __forceinline__ Row8 ld_row8(const float* __restrict__ X, int ldx,
                                        int gr, int M, int kc, int kend) {
  Row8 r;
  r.lo = make_float4(0.f, 0.f, 0.f, 0.f);
  r.hi = make_float4(0.f, 0.f, 0.f, 0.f);
  if (gr < M && kc < kend) {
    const float* xp = X + (size_t)gr * ldx + kc;
    if (kc + 8 <= kend) {
      if (AL16) {
        r.lo = ((const float4*)xp)[0];
        r.hi = ((const float4*)xp)[1];
      } else {  // rows 8B-aligned only (ldx=782, kc even)
        float2 a = *(const float2*)xp;
        float2 b = *(const float2*)(xp + 2);
        float2 c = *(const float2*)(xp + 4);
        float2 d = *(const float2*)(xp + 6);
        r.lo = make_float4(a.x, a.y, b.x, b.y);
        r.hi = make_float4(c.x, c.y, d.x, d.y);
      }
    } else {
      int rem = kend - kc;  // 1..7
      r.lo.x = xp[0];
      if (rem > 1) r.lo.y = xp[1];
      if (rem > 2) r.lo.z = xp[2];
      if (rem > 3) r.lo.w = xp[3];
      if (rem > 4) r.hi.x = xp[4];
      if (rem > 5) r.hi.y = xp[5];
      if (rem > 6) r.hi.z = xp[6];
    }
  }
  return r;
}

__device__ __forceinline__ float comp8(const Row8& r, int k) {  // k compile-time
  switch (k) {
    case 0: return r.lo.x; case 1: return r.lo.y;
    case 2: return r.lo.z; case 3: return r.lo.w;
    case 4: return r.hi.x; case 5: return r.hi.y;
    case 6: return r.hi.z; default: return r.hi.w;
  }
}

// grid-stride over (row-tile 256) x (col-tile TN) x (k-split). DIRECT: fused
// bias/relu to Y(ldy); else partials P[tz][M*Nd]. No early returns; barriers
// block-uniform.
template <int TN, bool AL16, bool DIRECT>
__device__ void gemm_stage(const float* __restrict__ X, int ldx,
                           const float* __restrict__ W, int ldw,
                           float* __restrict__ Y, int ldy,
                           const float* __restrict__ bias, int relu,
                           int M, int Kd, int Nd, int kchunk, int nk,
                           float* Ws) {
  int ntR = (M + NT - 1) / NT;
  int ntC = Nd / TN;  // exact for all uses
  int ntRC = ntR * ntC;
  int ntiles = ntRC * nk;
  constexpr int W4 = TN / 4;
  for (int tile = blockIdx.x; tile < ntiles; tile += gridDim.x) {
    int tz = tile / ntRC;
    int rm = tile - tz * ntRC;
    int tc = rm / ntR;
    int tr = rm - tc * ntR;
    int row0 = tr * NT;
    int col0 = tc * TN;
    int k0 = tz * kchunk;
    int kend = k0 + kchunk;
    if (kend > Kd) kend = Kd;
    int k8 = ((kend - k0) + 7) & ~7;
    __syncthreads();  // protect Ws from previous tile's readers
    for (int idx = threadIdx.x; idx < k8 * W4; idx += NT) {
      int wk = idx / W4;
      int wc = (idx - wk * W4) * 4;
      float4 wv = make_float4(0.f, 0.f, 0.f, 0.f);
      if (k0 + wk < kend)
        wv = *(const float4*)(W + (size_t)(k0 + wk) * ldw + col0 + wc);
      *(float4*)(Ws + wk * TN + wc) = wv;
    }
    __syncthreads();
    float acc[TN];
#pragma unroll
    for (int c = 0; c < TN; c++) acc[c] = 0.f;
    int r = row0 + threadIdx.x;
    int nch = k8 >> 3;
    Row8 cur = ld_row8<AL16>(X, ldx, r, M, k0, kend);
    for (int ci = 0; ci < nch; ci++) {
      Row8 nxt = cur;
      if (ci + 1 < nch) nxt = ld_row8<AL16>(X, ldx, r, M, k0 + (ci + 1) * 8, kend);
      int kb = ci << 3;
#pragma unroll
      for (int k = 0; k < 8; k++) {
        float x0 = comp8(cur, k);
        const float* wr = Ws + (kb + k) * TN;
#pragma unroll
        for (int c = 0; c < TN; c += 4) {
          float4 wv = *(const float4*)(wr + c);  // wave-uniform -> LDS broadcast
          acc[c + 0] += x0 * wv.x; acc[c + 1] += x0 * wv.y;
          acc[c + 2] += x0 * wv.z; acc[c + 3] += x0 * wv.w;
        }
      }
      cur = nxt;
    }
    if (r < M) {
      if (DIRECT) {
        float* yr = Y + (size_t)r * ldy + col0;
#pragma unroll
        for (int c = 0; c < TN; c += 4) {
          float4 v;
          v.x = acc[c + 0] + (bias ? bias[col0 + c + 0] : 0.f);
          v.y = acc[c + 1] + (bias ? bias[col0 + c + 1] : 0.f);
          v.z = acc[c + 2] + (bias ? bias[col0 + c + 2] : 0.f);
          v.w = acc[c + 3] + (bias ? bias[col0 + c + 3] : 0.f);
          if (relu) {
            v.x = fmaxf(v.x, 0.f); v.y = fmaxf(v.y, 0.f);
            v.z = fmaxf(v.z, 0.f); v.w = fmaxf(v.w, 0.f);
          }
          *(float4*)(yr + c) = v;
        }
      } else {
        float* pr = Y + ((size_t)tz * M + r) * Nd + col0;
#pragma unroll
        for (int c = 0; c < TN; c += 4)
          *(float4*)(pr + c) = make_float4(acc[c], acc[c + 1], acc[c + 2], acc[c + 3]);
      }
    }
  }
}

// ---- SpMM stage: wave-per-node grid-stride; S = sum dinv[src]*x;
//      u = -alpha*dinv[node]*S + beta*add + bias (+relu | softmax). ----
__device__ void spmm_stage(const int* __restrict__ cnt,
                           const int* __restrict__ bsrc,
                           const float* __restrict__ dinv,
                           const float* __restrict__ X, int ldx,
                           float* __restrict__ Y, int ldy,
                           const float* __restrict__ add, int lda,
                           const float* __restrict__ bias,
                           float alpha, float beta,
                           int C_log2, int Fstore, int relu, int do_softmax) {
  int wv = threadIdx.x >> 6;
  int lane = threadIdx.x & 63;
  int C = 1 << C_log2;
  int chunk = lane & (C - 1);
  int eslot = lane >> C_log2;
  int Epar = 64 >> C_log2;
  for (int node = blockIdx.x * 4 + wv; node < NN; node += gridDim.x * 4) {
    int cn = cnt[node]; if (cn > CAP) cn = CAP;
    float dn = dinv[node];
    int j0 = node << 7;
    int j1 = j0 + cn;
    float sx = 0.f, sy = 0.f, sz = 0.f, sw = 0.f;
    for (int j = j0 + eslot; j < j1; j += Epar) {
      int sn = bsrc[j];
      float w = dinv[sn];  // 40 KB table, cache-hot
      float4 xv = *(const float4*)(X + (size_t)sn * ldx + (chunk << 2));
      sx += w * xv.x; sy += w * xv.y; sz += w * xv.z; sw += w * xv.w;
    }
    for (int st = C; st < 64; st <<= 1) {
      sx += __shfl_xor(sx, st);
      sy += __shfl_xor(sy, st);
      sz += __shfl_xor(sz, st);
      sw += __shfl_xor(sw, st);
    }
    if (eslot == 0) {
      float am = -alpha * dn;
      int f0 = chunk << 2;
      float4 u = make_float4(am * sx, am * sy, am * sz, am * sw);
      if (add) {
        float4 av = *(const float4*)(add + (size_t)node * lda + f0);
        u.x += beta * av.x; u.y += beta * av.y; u.z += beta * av.z; u.w += beta * av.w;
      }
      if (bias) {
        if (f0 + 0 < Fstore) u.x += bias[f0 + 0];
        if (f0 + 1 < Fstore) u.y += bias[f0 + 1];
        if (f0 + 2 < Fstore) u.z += bias[f0 + 2];
        if (f0 + 3 < Fstore) u.w += bias[f0 + 3];
      }
      if (!do_softmax) {
        if (relu) {
          u.x = fmaxf(u.x, 0.f); u.y = fmaxf(u.y, 0.f);
          u.z = fmaxf(u.z, 0.f); u.w = fmaxf(u.w, 0.f);
        }
        if (f0 + 4 <= Fstore) {
          *(float4*)(Y + (size_t)node * ldy + f0) = u;
        } else {
          float vv[4] = {u.x, u.y, u.z, u.w};
#pragma unroll
          for (int c = 0; c < 4; c++)
            if (f0 + c < Fstore) Y[(size_t)node * ldy + f0 + c] = vv[c];
        }
      } else {
        float v[4] = {u.x, u.y, u.z, u.w};
        float mx = -INFINITY;
#pragma unroll
        for (int c = 0; c < 4; c++)
          if (f0 + c < Fstore) mx = fmaxf(mx, v[c]);
        mx = fmaxf(mx, __shfl_xor(mx, 1));
        mx = fmaxf(mx, __shfl_xor(mx, 2));
        mx = fmaxf(mx, __shfl_xor(mx, 4));
        float e[4];
        float s = 0.f;
#pragma unroll
        for (int c = 0; c < 4; c++) {
          e[c] = (f0 + c < Fstore) ? __expf(v[c] - mx) : 0.f;
          s += e[c];
        }
        s += __shfl_xor(s, 1);
        s += __shfl_xor(s, 2);
        s += __shfl_xor(s, 4);
        float inv = 1.f / s;
#pragma unroll
        for (int c = 0; c < 4; c++) {
          int f = f0 + c;
          if (f < Fstore) Y[(size_t)node * ldy + f] = e[c] * inv;
        }
      }
    }
  }
}

// ---------------- mega-kernel (cooperative): 18 stages, 17 grid syncs -------

__global__ __launch_bounds__(NT, 2) void mega_kernel(MegaParams p) {
  cg::grid_group g = cg::this_grid();
  __shared__ float Ws[72 * 48];  // max stage need (L1: k8=72 x TN=48 = 13.8 KB)

  stage_zero(p);                                   __threadfence(); g.sync();
  stage_count(p);                                  __threadfence(); g.sync();
  gemm_stage<48, false, false>(p.x, 782, p.wc1, 48, p.P, 0, nullptr, 0,
                               NN, 782, 48, L1_KCHUNK, L1_SPLITS, Ws);
                                                   __threadfence(); g.sync();
  stage_dinv_reduce(p);                            __threadfence(); g.sync();
  spmm_stage(p.cnt, p.bsrc, p.dinv, p.ABC1 + 32, 48, p.E1, 16,
             p.ABC1 + 16, 48, nullptr, 2.f, 1.f, 2, 16, 0, 0);
                                                   __threadfence(); g.sync();
  spmm_stage(p.cnt, p.bsrc, p.dinv, p.E1, 16, p.B2, 48,
             p.ABC1, 48, p.b1, 1.f, 1.f, 2, 16, 1, 0);
                                                   __threadfence(); g.sync();
  spmm_stage(p.cnt, p.bsrc, p.dinv, p.B2, 48, p.B2 + 16, 48,
             nullptr, 0, nullptr, 1.f, 0.f, 2, 16, 0, 0);
                                                   __threadfence(); g.sync();
  spmm_stage(p.cnt, p.bsrc, p.dinv, p.B2 + 16, 48, p.B2 + 32, 48,
             p.B2, 48, nullptr, 2.f, -1.f, 2, 16, 0, 0);
                                                   __threadfence(); g.sync();
  gemm_stage<32, true, true>(p.B2, 48, p.W2, 32, p.B3, 96, p.b2, 1,
                             NN, 48, 32, 48, 1, Ws);
                                                   __threadfence(); g.sync();
  spmm_stage(p.cnt, p.bsrc, p.dinv, p.B3, 96, p.B3 + 32, 96,
             nullptr, 0, nullptr, 1.f, 0.f, 3, 32, 0, 0);
                                                   __threadfence(); g.sync();
  spmm_stage(p.cnt, p.bsrc, p.dinv, p.B3 + 32, 96, p.B3 + 64, 96,
             p.B3, 96, nullptr, 2.f, -1.f, 3, 32, 0, 0);
                                                   __threadfence(); g.sync();
  gemm_stage<32, true, true>(p.B3, 96, p.W3, 64, p.B4, 192, p.b3, 1,
                             NN, 96, 64, 96, 1, Ws);
                                                   __threadfence(); g.sync();
  spmm_stage(p.cnt, p.bsrc, p.dinv, p.B4, 192, p.B4 + 64, 192,
             nullptr, 0, nullptr, 1.f, 0.f, 4, 64, 0, 0);
                                                   __threadfence(); g.sync();
  spmm_stage(p.cnt, p.bsrc, p.dinv, p.B4 + 64, 192, p.B4 + 128, 192,
             p.B4, 192, nullptr, 2.f, -1.f, 4, 64, 0, 0);
                                                   __threadfence(); g.sync();
  gemm_stage<16, true, true>(p.B4, 192, p.W4, 128, p.H4, 128, p.b4, 1,
                             NN, 192, 128, 192, 1, Ws);
                                                   __threadfence(); g.sync();
  gemm_stage<20, true, true>(p.H4, 128, p.wc5, 60, p.ABC5, 60, nullptr, 0,
                             NN, 128, 60, 128, 1, Ws);
                                                   __threadfence(); g.sync();
  spmm_stage(p.cnt, p.bsrc, p.dinv, p.ABC5 + 40, 60, p.E5, 32,
             p.ABC5 + 20, 60, nullptr, 2.f, 1.f, 3, 20, 0, 0);
                                                   __threadfence(); g.sync();
  spmm_stage(p.cnt, p.bsrc, p.dinv, p.E5, 32, p.out, 19,
             p.ABC5, 60, p.b5, 1.f, 1.f, 3, 19, 0, 1);
}

// ---------------- fallback kernels (same stage bodies, separate launches) ---

__global__ __launch_bounds__(NT) void fb_zero_k(MegaParams p) { stage_zero(p); }
__global__ __launch_bounds__(NT) void fb_count_k(MegaParams p) { stage_count(p); }
__global__ __launch_bounds__(NT) void fb_dinvred_k(MegaParams p) { stage_dinv_reduce(p); }

__global__ __launch_bounds__(NT, 2) void fb_gemm_l1_k(MegaParams p) {
  __shared__ float Ws[72 * 48];
  gemm_stage<48, false, false>(p.x, 782, p.wc1, 48, p.P, 0, nullptr, 0,
                               NN, 782, 48, L1_KCHUNK, L1_SPLITS, Ws);
}
__global__ __launch_bounds__(NT, 2) void fb_gemm32_k(
    const float* X, int ldx, const float* W, int ldw, float* Y, int ldy,
    const float* bias, int relu, int Kd, int Nd) {
  __shared__ float Ws[96 * 32];
  gemm_stage<32, true, true>(X, ldx, W, ldw, Y, ldy, bias, relu, NN, Kd, Nd, Kd, 1, Ws);
}
__global__ __launch_bounds__(NT, 2) void fb_gemm16_k(
    const float* X, int ldx, const float* W, int ldw, float* Y, int ldy,
    const float* bias, int relu, int Kd, int Nd) {
  __shared__ float Ws[192 * 16];
  gemm_stage<16, true, true>(X, ldx, W, ldw, Y, ldy, bias, relu, NN, Kd, Nd, Kd, 1, Ws);
}
__global__ __launch_bounds__(NT, 2) void fb_gemm20_k(
    const float* X, int ldx, const float* W, int ldw, float* Y, int ldy,
    const float* bias, int relu, int Kd, int Nd) {
  __shared__ float Ws[128 * 20];
  gemm_stage<20, true, true>(X, ldx, W, ldw, Y, ldy, bias, relu, NN, Kd, Nd, Kd, 1, Ws);
}
__global__ __launch_bounds__(NT) void fb_spmm_k(
    const int* cnt, const int* bsrc, const float* dinv,
    const float* X, int ldx, float* Y, int ldy,
    const float* add, int lda, const float* bias,
    float alpha, float beta, int C_log2, int Fstore, int relu, int do_softmax) {
  spmm_stage(cnt, bsrc, dinv, X, ldx, Y, ldy, add, lda, bias,
             alpha, beta, C_log2, Fstore, relu, do_softmax);
}

// ---------------- host ----------------

extern "C" void kernel_launch(void* const* d_in, const int* in_sizes, int n_in,
                              void* d_out, int out_size, void* d_ws, size_t ws_size,
                              hipStream_t stream) {
  (void)in_sizes; (void)n_in; (void)out_size; (void)ws_size;
  char* p = (char*)d_ws;
  auto alloc = [&](size_t bytes) {
    char* r = p;
    p += (bytes + 255) & ~(size_t)255;
    return r;
  };
  int*   i_deg  = (int*)alloc(sizeof(int) * NN * 2);  // deg, cnt contiguous
  int*   i_bsrc = (int*)alloc(sizeof(int) * NN * CAP);
  float* f_dinv = (float*)alloc(sizeof(float) * NN);
  float* wc1    = (float*)alloc(sizeof(float) * WC1_TOTAL);
  float* wc5    = (float*)alloc(sizeof(float) * WC5_TOTAL);
  float* R1     = (float*)alloc(sizeof(float) * NN * 96);
  float* R2     = (float*)alloc(sizeof(float) * NN * 192);
  float* R3     = (float*)alloc(sizeof(float) * NN * 128);
  float* P      = (float*)alloc(sizeof(float) * NN * 48 * L1_SPLITS);

  MegaParams mp;
  mp.x   = (const float*)d_in[0];
  const int* ei = (const int*)d_in[1];
  mp.src = ei;
  mp.dst = ei + NE;
  mp.W1 = (const float*)d_in[2];  mp.b1 = (const float*)d_in[3];
  mp.W2 = (const float*)d_in[4];  mp.b2 = (const float*)d_in[5];
  mp.W3 = (const float*)d_in[6];  mp.b3 = (const float*)d_in[7];
  mp.W4 = (const float*)d_in[8];  mp.b4 = (const float*)d_in[9];
  mp.W5 = (const float*)d_in[10]; mp.b5 = (const float*)d_in[11];
  mp.deg = i_deg; mp.cnt = i_deg + NN; mp.bsrc = i_bsrc;
  mp.dinv = f_dinv; mp.wc1 = wc1; mp.wc5 = wc5;
  mp.ABC1 = R1; mp.B3 = R1; mp.ABC5 = R1;
  mp.E1 = R2;   mp.B4 = R2; mp.E5 = R2;
  mp.B2 = R3;   mp.H4 = R3;
  mp.P = P;
  mp.out = (float*)d_out;

  // --- decide path from host-side queries only (no trial launches) ---
  int occ = 0;
  hipError_t oe = hipOccupancyMaxActiveBlocksPerMultiprocessor(&occ, mega_kernel, NT, 0);
  int nCU = 0;
  {
    int dev = 0;
    hipGetDevice(&dev);
    hipDeviceProp_t prop;
    if (hipGetDeviceProperties(&prop, dev) == hipSuccess)
      nCU = prop.multiProcessorCount;
  }
  long maxCoop = (oe == hipSuccess && occ > 0 && nCU > 0) ? (long)occ * nCU : 0;

  if (maxCoop >= 128) {
    int grid = (int)(maxCoop < 512 ? maxCoop : 512);
    void* args[] = { &mp };
    hipLaunchCooperativeKernel(mega_kernel, dim3(grid), dim3(NT), args, 0, stream);
  } else {
    // ---- fallback: identical stages, 18 plain launches ----
    fb_zero_k<<<256, NT, 0, stream>>>(mp);
    fb_count_k<<<(NE + NT - 1) / NT, NT, 0, stream>>>(mp);
    fb_gemm_l1_k<<<480, NT, 0, stream>>>(mp);
    fb_dinvred_k<<<(NN * 48 + NT - 1) / NT, NT, 0, stream>>>(mp);
    fb_spmm_k<<<2500, NT, 0, stream>>>(mp.cnt, mp.bsrc, mp.dinv, mp.ABC1 + 32, 48,
                                       mp.E1, 16, mp.ABC1 + 16, 48, nullptr,
                                       2.f, 1.f, 2, 16, 0, 0);
    fb_spmm_k<<<2500, NT, 0, stream>>>(mp.cnt, mp.bsrc, mp.dinv, mp.E1, 16,
                                       mp.B2, 48, mp.ABC1, 48, mp.b1,
                                       1.f, 1.f, 2, 16, 1, 0);
    fb_spmm_k<<<2500, NT, 0, stream>>>(mp.cnt, mp.bsrc, mp.dinv, mp.B2, 48,
                                       mp.B2 + 16, 48, nullptr, 0, nullptr,
                                       1.f, 0.f, 2, 16, 0, 0);
    fb_spmm_k<<<2500, NT, 0, stream>>>(mp.cnt, mp.bsrc, mp.dinv, mp.B2 + 16, 48,
                                       mp.B2 + 32, 48, mp.B2, 48, nullptr,
                                       2.f, -1.f, 2, 16, 0, 0);
    fb_gemm32_k<<<40, NT, 0, stream>>>(mp.B2, 48, mp.W2, 32, mp.B3, 96, mp.b2, 1, 48, 32);
    fb_spmm_k<<<2500, NT, 0, stream>>>(mp.cnt, mp.bsrc, mp.dinv, mp.B3, 96,
                                       mp.B3 + 32, 96, nullptr, 0, nullptr,
                                       1.f, 0.f, 3, 32, 0, 0);
    fb_spmm_k<<<2500, NT, 0, stream>>>(mp.cnt, mp.bsrc, mp.dinv, mp.B3 + 32, 96,
                                       mp.B3 + 64, 96, mp.B3, 96, nullptr,
                                       2.f, -1.f, 3, 32, 0, 0);
    fb_gemm32_k<<<80, NT, 0, stream>>>(mp.B3, 96, mp.W3, 64, mp.B4, 192, mp.b3, 1, 96, 64);
    fb_spmm_k<<<2500, NT, 0, stream>>>(mp.cnt, mp.bsrc, mp.dinv, mp.B4, 192,
                                       mp.B4 + 64, 192, nullptr, 0, nullptr,
                                       1.f, 0.f, 4, 64, 0, 0);
    fb_spmm_k<<<2500, NT, 0, stream>>>(mp.cnt, mp.bsrc, mp.dinv, mp.B4 + 64, 192,
                                       mp.B4 + 128, 192, mp.B4, 192, nullptr,
                                       2.f, -1.f, 4, 64, 0, 0);
    fb_gemm16_k<<<320, NT, 0, stream>>>(mp.B4, 192, mp.W4, 128, mp.H4, 128, mp.b4, 1,
                                        192, 128);
    fb_gemm20_k<<<120, NT, 0, stream>>>(mp.H4, 128, mp.wc5, 60, mp.ABC5, 60, nullptr, 0,
                                        128, 60);
    fb_spmm_k<<<2500, NT, 0, stream>>>(mp.cnt, mp.bsrc, mp.dinv, mp.ABC5 + 40, 60,
                                       mp.E5, 32, mp.ABC5 + 20, 60, nullptr,
                                       2.f, 1.f, 3, 20, 0, 0);
    fb_spmm_k<<<2500, NT, 0, stream>>>(mp.cnt, mp.bsrc, mp.dinv, mp.E5, 32,
                                       mp.out, 19, mp.ABC5, 60, mp.b5,
                                       1.f, 1.f, 3, 19, 0, 1);
  }
}

// Round 13
// 273.743 us; speedup vs baseline: 4.9828x; 4.9828x over previous
//
#include <hip/hip_runtime.h>
#include <math.h>

#define NN 10000
#define NE 160000
#define CAP 128     // bucket capacity; P(in-deg >= 128 | Poisson(16)) ~ 1e-60
#define NT 256
#define WC1_TOTAL (782 * 48)
#define WC5_TOTAL (128 * 60)
#define L1_SPLITS 12
#define L1_KCHUNK 66   // even (float2 path); 12*66 >= 782
#define CNT_BLKS 625   // 625*256 == NE exactly

struct MegaParams {
  const float* x;
  const int* src;
  const int* dst;
  const float* W1; const float* b1;
  const float* W2; const float* b2;
  const float* W3; const float* b3;
  const float* W4; const float* b4;
  const float* W5; const float* b5;
  int* deg; int* cnt; int* bsrc;
  float* dinv; float* wc1; float* wc5;
  float* ABC1; float* E1; float* B2; float* B3; float* B4;
  float* H4; float* ABC5; float* E5; float* P;
  float* out;
};

// ---- weight concat: Wc [Fin][3*Fp]: [W0-W2 | W1 | W2], pad cols zero ----
__device__ __forceinline__ void wcat_one(const float* __restrict__ W,
                                         float* __restrict__ Wc,
                                         int i, int Fin, int F, int Fp) {
  int w3 = 3 * Fp;
  int row = i / w3;
  int c = i - row * w3;
  int sec = c / Fp;
  int f = c - sec * Fp;
  float v = 0.0f;
  if (f < F) {
    if (sec == 0)      v = W[row * F + f] - W[2 * Fin * F + row * F + f];
    else if (sec == 1) v = W[Fin * F + row * F + f];
    else               v = W[2 * Fin * F + row * F + f];
  }
  Wc[i] = v;
}

// ---- GEMM stage (register-X prefetch, LDS-W broadcast, RT=1) ----
// Bodies identical to the mega-verified round-12 versions (correctness proven
// on-device); only the tile indexing is parameterized for grid packing.
struct Row8 { float4 lo, hi; };

template <bool AL16>
__device__ __forceinline__ Row8 ld_row8(const float* __restrict__ X, int ldx,
                                        int gr, int M, int kc, int kend) {
  Row8 r;
  r.lo = make_float4(0.f, 0.f, 0.f, 0.f);
  r.hi = make_float4(0.f, 0.f, 0.f, 0.f);
  if (gr < M && kc < kend) {
    const float* xp = X + (size_t)gr * ldx + kc;
    if (kc + 8 <= kend) {
      if (AL16) {
        r.lo = ((const float4*)xp)[0];
        r.hi = ((const float4*)xp)[1];
      } else {  // rows 8B-aligned only (ldx=782, kc even)
        float2 a = *(const float2*)xp;
        float2 b = *(const float2*)(xp + 2);
        float2 c = *(const float2*)(xp + 4);
        float2 d = *(const float2*)(xp + 6);
        r.lo = make_float4(a.x, a.y, b.x, b.y);
        r.hi = make_float4(c.x, c.y, d.x, d.y);
      }
    } else {
      int rem = kend - kc;  // 1..7
      r.lo.x = xp[0];
      if (rem > 1) r.lo.y = xp[1];
      if (rem > 2) r.lo.z = xp[2];
      if (rem > 3) r.lo.w = xp[3];
      if (rem > 4) r.hi.x = xp[4];
      if (rem > 5) r.hi.y = xp[5];
      if (rem > 6) r.hi.z = xp[6];
    }
  }
  return r;
}

__device__ __forceinline__ float comp8(const Row8& r, int k) {  // k compile-time
  switch (k) {
    case 0: return r.lo.x; case 1: return r.lo.y;
    case 2: return r.lo.z; case 3: return r.lo.w;
    case 4: return r.hi.x; case 5: return r.hi.y;
    case 6: return r.hi.z; default: return r.hi.w;
  }
}

// tiles over (row-tile 256) x (col-tile TN) x (k-split), iterated from tile0
// by tstride. DIRECT: fused bias/relu to Y(ldy); else partials P[tz][M*Nd].
template <int TN, bool AL16, bool DIRECT>
__device__ void gemm_stage(const float* __restrict__ X, int ldx,
                           const float* __restrict__ W, int ldw,
                           float* __restrict__ Y, int ldy,
                           const float* __restrict__ bias, int relu,
                           int M, int Kd, int Nd, int kchunk, int nk,
                           int tile0, int tstride, float* Ws) {
  int ntR = (M + NT - 1) / NT;
  int ntC = Nd / TN;  // exact for all uses
  int ntRC = ntR * ntC;
  int ntiles = ntRC * nk;
  constexpr int W4 = TN / 4;
  for (int tile = tile0; tile < ntiles; tile += tstride) {
    int tz = tile / ntRC;
    int rm = tile - tz * ntRC;
    int tc = rm / ntR;
    int tr = rm - tc * ntR;
    int row0 = tr * NT;
    int col0 = tc * TN;
    int k0 = tz * kchunk;
    int kend = k0 + kchunk;
    if (kend > Kd) kend = Kd;
    int k8 = ((kend - k0) + 7) & ~7;
    __syncthreads();  // protect Ws from previous tile's readers
    for (int idx = threadIdx.x; idx < k8 * W4; idx += NT) {
      int wk = idx / W4;
      int wc = (idx - wk * W4) * 4;
      float4 wv = make_float4(0.f, 0.f, 0.f, 0.f);
      if (k0 + wk < kend)
        wv = *(const float4*)(W + (size_t)(k0 + wk) * ldw + col0 + wc);
      *(float4*)(Ws + wk * TN + wc) = wv;
    }
    __syncthreads();
    float acc[TN];
#pragma unroll
    for (int c = 0; c < TN; c++) acc[c] = 0.f;
    int r = row0 + threadIdx.x;
    int nch = k8 >> 3;
    Row8 cur = ld_row8<AL16>(X, ldx, r, M, k0, kend);
    for (int ci = 0; ci < nch; ci++) {
      Row8 nxt = cur;
      if (ci + 1 < nch) nxt = ld_row8<AL16>(X, ldx, r, M, k0 + (ci + 1) * 8, kend);
      int kb = ci << 3;
#pragma unroll
      for (int k = 0; k < 8; k++) {
        float x0 = comp8(cur, k);
        const float* wr = Ws + (kb + k) * TN;
#pragma unroll
        for (int c = 0; c < TN; c += 4) {
          float4 wv = *(const float4*)(wr + c);  // wave-uniform -> LDS broadcast
          acc[c + 0] += x0 * wv.x; acc[c + 1] += x0 * wv.y;
          acc[c + 2] += x0 * wv.z; acc[c + 3] += x0 * wv.w;
        }
      }
      cur = nxt;
    }
    if (r < M) {
      if (DIRECT) {
        float* yr = Y + (size_t)r * ldy + col0;
#pragma unroll
        for (int c = 0; c < TN; c += 4) {
          float4 v;
          v.x = acc[c + 0] + (bias ? bias[col0 + c + 0] : 0.f);
          v.y = acc[c + 1] + (bias ? bias[col0 + c + 1] : 0.f);
          v.z = acc[c + 2] + (bias ? bias[col0 + c + 2] : 0.f);
          v.w = acc[c + 3] + (bias ? bias[col0 + c + 3] : 0.f);
          if (relu) {
            v.x = fmaxf(v.x, 0.f); v.y = fmaxf(v.y, 0.f);
            v.z = fmaxf(v.z, 0.f); v.w = fmaxf(v.w, 0.f);
          }
          *(float4*)(yr + c) = v;
        }
      } else {
        float* pr = Y + ((size_t)tz * M + r) * Nd + col0;
#pragma unroll
        for (int c = 0; c < TN; c += 4)
          *(float4*)(pr + c) = make_float4(acc[c], acc[c + 1], acc[c + 2], acc[c + 3]);
      }
    }
  }
}

// ---- SpMM stage: wave-per-node grid-stride; S = sum dinv[src]*x;
//      u = -alpha*dinv[node]*S + beta*add + bias (+relu | softmax). ----
__device__ void spmm_stage(const int* __restrict__ cnt,
                           const int* __restrict__ bsrc,
                           const float* __restrict__ dinv,
                           const float* __restrict__ X, int ldx,
                           float* __restrict__ Y, int ldy,
                           const float* __restrict__ add, int lda,
                           const float* __restrict__ bias,
                           float alpha, float beta,
                           int C_log2, int Fstore, int relu, int do_softmax) {
  int wv = threadIdx.x >> 6;
  int lane = threadIdx.x & 63;
  int C = 1 << C_log2;
  int chunk = lane & (C - 1);
  int eslot = lane >> C_log2;
  int Epar = 64 >> C_log2;
  for (int node = blockIdx.x * 4 + wv; node < NN; node += gridDim.x * 4) {
    int cn = cnt[node]; if (cn > CAP) cn = CAP;
    float dn = dinv[node];
    int j0 = node << 7;
    int j1 = j0 + cn;
    float sx = 0.f, sy = 0.f, sz = 0.f, sw = 0.f;
    for (int j = j0 + eslot; j < j1; j += Epar) {
      int sn = bsrc[j];
      float w = dinv[sn];  // 40 KB table, cache-hot
      float4 xv = *(const float4*)(X + (size_t)sn * ldx + (chunk << 2));
      sx += w * xv.x; sy += w * xv.y; sz += w * xv.z; sw += w * xv.w;
    }
    for (int st = C; st < 64; st <<= 1) {
      sx += __shfl_xor(sx, st);
      sy += __shfl_xor(sy, st);
      sz += __shfl_xor(sz, st);
      sw += __shfl_xor(sw, st);
    }
    if (eslot == 0) {
      float am = -alpha * dn;
      int f0 = chunk << 2;
      float4 u = make_float4(am * sx, am * sy, am * sz, am * sw);
      if (add) {
        float4 av = *(const float4*)(add + (size_t)node * lda + f0);
        u.x += beta * av.x; u.y += beta * av.y; u.z += beta * av.z; u.w += beta * av.w;
      }
      if (bias) {
        if (f0 + 0 < Fstore) u.x += bias[f0 + 0];
        if (f0 + 1 < Fstore) u.y += bias[f0 + 1];
        if (f0 + 2 < Fstore) u.z += bias[f0 + 2];
        if (f0 + 3 < Fstore) u.w += bias[f0 + 3];
      }
      if (!do_softmax) {
        if (relu) {
          u.x = fmaxf(u.x, 0.f); u.y = fmaxf(u.y, 0.f);
          u.z = fmaxf(u.z, 0.f); u.w = fmaxf(u.w, 0.f);
        }
        if (f0 + 4 <= Fstore) {
          *(float4*)(Y + (size_t)node * ldy + f0) = u;
        } else {
          float vv[4] = {u.x, u.y, u.z, u.w};
#pragma unroll
          for (int c = 0; c < 4; c++)
            if (f0 + c < Fstore) Y[(size_t)node * ldy + f0 + c] = vv[c];
        }
      } else {
        float v[4] = {u.x, u.y, u.z, u.w};
        float mx = -INFINITY;
#pragma unroll
        for (int c = 0; c < 4; c++)
          if (f0 + c < Fstore) mx = fmaxf(mx, v[c]);
        mx = fmaxf(mx, __shfl_xor(mx, 1));
        mx = fmaxf(mx, __shfl_xor(mx, 2));
        mx = fmaxf(mx, __shfl_xor(mx, 4));
        float e[4];
        float s = 0.f;
#pragma unroll
        for (int c = 0; c < 4; c++) {
          e[c] = (f0 + c < Fstore) ? __expf(v[c] - mx) : 0.f;
          s += e[c];
        }
        s += __shfl_xor(s, 1);
        s += __shfl_xor(s, 2);
        s += __shfl_xor(s, 4);
        float inv = 1.f / s;
#pragma unroll
        for (int c = 0; c < 4; c++) {
          int f = f0 + c;
          if (f < Fstore) Y[(size_t)node * ldy + f] = e[c] * inv;
        }
      }
    }
  }
}

// ---------------- kernels (17-dispatch chain; no cooperative launch) --------
// Learning (round 12): grid.sync() costs ~100 us on MI355X -> plain launches.

// L0: zero deg/cnt + both weight concats
__global__ __launch_bounds__(NT) void k_zero_wcat(MegaParams p) {
  int tid = blockIdx.x * NT + threadIdx.x;
  int TT = gridDim.x * NT;
  for (int i = tid; i < 2 * NN; i += TT) p.deg[i] = 0;  // deg+cnt contiguous
  for (int i = tid; i < WC1_TOTAL; i += TT) wcat_one(p.W1, p.wc1, i, 782, 16, 16);
  for (int i = tid; i < WC5_TOTAL; i += TT) wcat_one(p.W5, p.wc5, i, 128, 19, 20);
}

// L1: degree count + bucket insert (blocks 0..624) PACKED with
//     L1-GEMM k-split partials (blocks 625..1104) — mutually independent.
__global__ __launch_bounds__(NT) void k_count_gemm1(MegaParams p) {
  __shared__ float Ws[72 * 48];  // 13.8 KB (gemm branch only)
  if (blockIdx.x < CNT_BLKS) {
    int e = blockIdx.x * NT + threadIdx.x;  // 0..159999 exactly
    int s = p.src[e], d = p.dst[e];
    atomicAdd(&p.deg[s], 1);
    int slot = atomicAdd(&p.cnt[d], 1);
    if (slot < CAP) p.bsrc[(d << 7) + slot] = s;
  } else {
    gemm_stage<48, false, false>(p.x, 782, p.wc1, 48, p.P, 0, nullptr, 0,
                                 NN, 782, 48, L1_KCHUNK, L1_SPLITS,
                                 blockIdx.x - CNT_BLKS, 1 << 30, Ws);
  }
}

// L2: dinv + reduce ABC1
__global__ __launch_bounds__(NT) void k_reduce_dinv(MegaParams p) {
  int tid = blockIdx.x * NT + threadIdx.x;
  int TT = gridDim.x * NT;
  for (int i = tid; i < NN; i += TT) {
    int d = p.deg[i];
    p.dinv[i] = d > 0 ? 1.0f / sqrtf((float)d) : 0.0f;
  }
  for (int i = tid; i < NN * 48; i += TT) {
    float s = 0.f;
#pragma unroll
    for (int z = 0; z < L1_SPLITS; z++) s += p.P[(size_t)z * (NN * 48) + i];
    p.ABC1[i] = s;
  }
}

// SpMM launcher kernel
__global__ __launch_bounds__(NT) void k_spmm(
    const int* cnt, const int* bsrc, const float* dinv,
    const float* X, int ldx, float* Y, int ldy,
    const float* add, int lda, const float* bias,
    float alpha, float beta, int C_log2, int Fstore, int relu, int do_softmax) {
  spmm_stage(cnt, bsrc, dinv, X, ldx, Y, ldy, add, lda, bias,
             alpha, beta, C_log2, Fstore, relu, do_softmax);
}

// Direct GEMM launcher kernels (full-K, fused bias/relu)
__global__ __launch_bounds__(NT, 2) void k_gemm32(
    const float* X, int ldx, const float* W, int ldw, float* Y, int ldy,
    const float* bias, int relu, int Kd, int Nd) {
  __shared__ float Ws[96 * 32];
  gemm_stage<32, true, true>(X, ldx, W, ldw, Y, ldy, bias, relu,
                             NN, Kd, Nd, Kd, 1, blockIdx.x, gridDim.x, Ws);
}
__global__ __launch_bounds__(NT, 2) void k_gemm16(
    const float* X, int ldx, const float* W, int ldw, float* Y, int ldy,
    const float* bias, int relu, int Kd, int Nd) {
  __shared__ float Ws[192 * 16];
  gemm_stage<16, true, true>(X, ldx, W, ldw, Y, ldy, bias, relu,
                             NN, Kd, Nd, Kd, 1, blockIdx.x, gridDim.x, Ws);
}
__global__ __launch_bounds__(NT, 2) void k_gemm20(
    const float* X, int ldx, const float* W, int ldw, float* Y, int ldy,
    const float* bias, int relu, int Kd, int Nd) {
  __shared__ float Ws[128 * 20];
  gemm_stage<20, true, true>(X, ldx, W, ldw, Y, ldy, bias, relu,
                             NN, Kd, Nd, Kd, 1, blockIdx.x, gridDim.x, Ws);
}

// ---------------- host ----------------

extern "C" void kernel_launch(void* const* d_in, const int* in_sizes, int n_in,
                              void* d_out, int out_size, void* d_ws, size_t ws_size,
                              hipStream_t stream) {
  (void)in_sizes; (void)n_in; (void)out_size; (void)ws_size;
  char* p = (char*)d_ws;
  auto alloc = [&](size_t bytes) {
    char* r = p;
    p += (bytes + 255) & ~(size_t)255;
    return r;
  };
  int*   i_deg  = (int*)alloc(sizeof(int) * NN * 2);  // deg, cnt contiguous
  int*   i_bsrc = (int*)alloc(sizeof(int) * NN * CAP);
  float* f_dinv = (float*)alloc(sizeof(float) * NN);
  float* wc1    = (float*)alloc(sizeof(float) * WC1_TOTAL);
  float* wc5    = (float*)alloc(sizeof(float) * WC5_TOTAL);
  float* R1     = (float*)alloc(sizeof(float) * NN * 96);   // ABC1(48)->B3(96)->ABC5(60)
  float* R2     = (float*)alloc(sizeof(float) * NN * 192);  // E1(16)->B4(192)->E5(32)
  float* R3     = (float*)alloc(sizeof(float) * NN * 128);  // B2(48)->H4(128)
  float* P      = (float*)alloc(sizeof(float) * NN * 48 * L1_SPLITS);

  MegaParams mp;
  mp.x   = (const float*)d_in[0];
  const int* ei = (const int*)d_in[1];
  mp.src = ei;
  mp.dst = ei + NE;
  mp.W1 = (const float*)d_in[2];  mp.b1 = (const float*)d_in[3];
  mp.W2 = (const float*)d_in[4];  mp.b2 = (const float*)d_in[5];
  mp.W3 = (const float*)d_in[6];  mp.b3 = (const float*)d_in[7];
  mp.W4 = (const float*)d_in[8];  mp.b4 = (const float*)d_in[9];
  mp.W5 = (const float*)d_in[10]; mp.b5 = (const float*)d_in[11];
  mp.deg = i_deg; mp.cnt = i_deg + NN; mp.bsrc = i_bsrc;
  mp.dinv = f_dinv; mp.wc1 = wc1; mp.wc5 = wc5;
  mp.ABC1 = R1; mp.B3 = R1; mp.ABC5 = R1;
  mp.E1 = R2;   mp.B4 = R2; mp.E5 = R2;
  mp.B2 = R3;   mp.H4 = R3;
  mp.P = P;
  mp.out = (float*)d_out;

  // L0: zero + wcat
  k_zero_wcat<<<160, NT, 0, stream>>>(mp);
  // L1: count (625 blocks) + L1-GEMM partials (480 tiles)
  k_count_gemm1<<<CNT_BLKS + 480, NT, 0, stream>>>(mp);
  // L2: dinv + reduce ABC1
  k_reduce_dinv<<<(NN * 48 + NT - 1) / NT, NT, 0, stream>>>(mp);
  // L3: E1 = 2*L(C) + B
  k_spmm<<<2500, NT, 0, stream>>>(mp.cnt, mp.bsrc, mp.dinv, mp.ABC1 + 32, 48,
                                  mp.E1, 16, mp.ABC1 + 16, 48, nullptr,
                                  2.f, 1.f, 2, 16, 0, 0);
  // L4: H1 = relu(L(E1) + A + b1) -> B2 slot0 (ld48)
  k_spmm<<<2500, NT, 0, stream>>>(mp.cnt, mp.bsrc, mp.dinv, mp.E1, 16,
                                  mp.B2, 48, mp.ABC1, 48, mp.b1,
                                  1.f, 1.f, 2, 16, 1, 0);
  // L5/L6: layer-2 T1, T2 in B2 (ld48)
  k_spmm<<<2500, NT, 0, stream>>>(mp.cnt, mp.bsrc, mp.dinv, mp.B2, 48,
                                  mp.B2 + 16, 48, nullptr, 0, nullptr,
                                  1.f, 0.f, 2, 16, 0, 0);
  k_spmm<<<2500, NT, 0, stream>>>(mp.cnt, mp.bsrc, mp.dinv, mp.B2 + 16, 48,
                                  mp.B2 + 32, 48, mp.B2, 48, nullptr,
                                  2.f, -1.f, 2, 16, 0, 0);
  // L7: H2 = relu(B2 @ W2 + b2) -> B3 slot0 (ld96)
  k_gemm32<<<40, NT, 0, stream>>>(mp.B2, 48, mp.W2, 32, mp.B3, 96, mp.b2, 1, 48, 32);
  // L8/L9: layer-3 T1, T2 in B3 (ld96)
  k_spmm<<<2500, NT, 0, stream>>>(mp.cnt, mp.bsrc, mp.dinv, mp.B3, 96,
                                  mp.B3 + 32, 96, nullptr, 0, nullptr,
                                  1.f, 0.f, 3, 32, 0, 0);
  k_spmm<<<2500, NT, 0, stream>>>(mp.cnt, mp.bsrc, mp.dinv, mp.B3 + 32, 96,
                                  mp.B3 + 64, 96, mp.B3, 96, nullptr,
                                  2.f, -1.f, 3, 32, 0, 0);
  // L10: H3 = relu(B3 @ W3 + b3) -> B4 slot0 (ld192)
  k_gemm32<<<80, NT, 0, stream>>>(mp.B3, 96, mp.W3, 64, mp.B4, 192, mp.b3, 1, 96, 64);
  // L11/L12: layer-4 T1, T2 in B4 (ld192)
  k_spmm<<<2500, NT, 0, stream>>>(mp.cnt, mp.bsrc, mp.dinv, mp.B4, 192,
                                  mp.B4 + 64, 192, nullptr, 0, nullptr,
                                  1.f, 0.f, 4, 64, 0, 0);
  k_spmm<<<2500, NT, 0, stream>>>(mp.cnt, mp.bsrc, mp.dinv, mp.B4 + 64, 192,
                                  mp.B4 + 128, 192, mp.B4, 192, nullptr,
                                  2.f, -1.f, 4, 64, 0, 0);
  // L13: H4 = relu(B4 @ W4 + b4) (ld128), direct full-K (no split/reduce)
  k_gemm16<<<320, NT, 0, stream>>>(mp.B4, 192, mp.W4, 128, mp.H4, 128, mp.b4, 1,
                                   192, 128);
  // L14: ABC5 = H4 @ wc5 (ld60)
  k_gemm20<<<120, NT, 0, stream>>>(mp.H4, 128, mp.wc5, 60, mp.ABC5, 60, nullptr, 0,
                                   128, 60);
  // L15: E5 = 2*L(C) + B (Fstore 20; cols >= 20 masked)
  k_spmm<<<2500, NT, 0, stream>>>(mp.cnt, mp.bsrc, mp.dinv, mp.ABC5 + 40, 60,
                                  mp.E5, 32, mp.ABC5 + 20, 60, nullptr,
                                  2.f, 1.f, 3, 20, 0, 0);
  // L16: out = softmax(L(E5) + A + b5) (ld19)
  k_spmm<<<2500, NT, 0, stream>>>(mp.cnt, mp.bsrc, mp.dinv, mp.E5, 32,
                                  mp.out, 19, mp.ABC5, 60, mp.b5,
                                  1.f, 1.f, 3, 19, 0, 1);
}